// Round 1
// baseline (96.119 us; speedup 1.0000x reference)
//
#include <hip/hip_runtime.h>

// out[n,m] = exp(-0.5 * sum_d (x[n,d]-c[m,d])^2 / s2[m,d]) / sqrt((2pi)^D * prod s2[m,d])
// Fast path (per-center d-uniform variance; true for bench sigma==1):
//   out = exp2( L2E*(x.a) + qc*r2[n] + c0 ),  a = c/s2, qc = -0.5*L2E/s2,
//   c0 = -0.5*L2E*(c.a) - 0.5*(D*log2(2pi) + sum log2 s2),  r2[n] = sum_d x^2
//
// Round 5: the x-tile is staged in LDS once per block (it was re-read from
// global every row; 4 blocks/CU x 8KB tiles + streaming stores thrash the
// 32KB L1 -> L2-latency-bound inner loop at only 4 waves/SIMD). Inner loop
// now does uniform-address ds_read_b128 broadcasts (conflict-free), 4 rows
// per iteration for ILP. A[] stays pinned in VGPRs (round-4 fix).

#define N_  16384
#define M_  1024
#define D_  32
#define NT  64      // grid = (4, 256) = 1024 blocks = 4 blocks/CU exactly
#define BLK 256

typedef float v2f __attribute__((ext_vector_type(2)));
typedef float v4f __attribute__((ext_vector_type(4)));
#define PIN(v) asm volatile("" : "+v"(v))

__global__ __launch_bounds__(BLK, 4) void rbf_kernel(
    const float* __restrict__ x, const float* __restrict__ centers,
    const float* __restrict__ sigma, float* __restrict__ out)
{
    const int tid = threadIdx.x;
    const int m   = blockIdx.x * BLK + tid;
    const int n0  = blockIdx.y * NT;

    __shared__ __align__(16) float xs[NT * D_];   // 8 KB x-tile
    __shared__ __align__(16) float r2s[NT];

    // Cooperative stage: 256 threads x 2 float4 = 8 KB, fully coalesced.
    // r2 is folded into the staging pass via an 8-lane shuffle reduction
    // (float4 #k covers row k/8; 8 consecutive lanes share a row, never
    // crossing a wave boundary).
    {
        const float4* xg  = (const float4*)(x + (size_t)n0 * D_);
        float4*       xsv = (float4*)xs;
        float4 v0 = xg[tid];
        float4 v1 = xg[tid + BLK];
        xsv[tid]       = v0;
        xsv[tid + BLK] = v1;
        float s0 = fmaf(v0.x, v0.x, fmaf(v0.y, v0.y, fmaf(v0.z, v0.z, v0.w * v0.w)));
        float s1 = fmaf(v1.x, v1.x, fmaf(v1.y, v1.y, fmaf(v1.z, v1.z, v1.w * v1.w)));
        #pragma unroll
        for (int off = 1; off < 8; off <<= 1) {
            s0 += __shfl_xor(s0, off);
            s1 += __shfl_xor(s1, off);
        }
        if ((tid & 7) == 0) {
            r2s[tid >> 3]        = s0;   // rows 0..31
            r2s[(tid >> 3) + 32] = s1;   // rows 32..63
        }
    }
    __syncthreads();

    const float L2E      = 1.4426950408889634f;   // log2(e)
    const float LOG2_2PI = 2.6514961294723187f;   // log2(2*pi)

    // sigma scan: d-uniform check + log-determinant (exactly 0 for sigma==1)
    float s2_0 = 0.f, ld = 0.f;
    bool uf = true;
    {
        const float* sg = sigma + (size_t)m * D_;
        #pragma unroll
        for (int d = 0; d < D_; ++d) {
            float s  = sg[d];
            float s2 = s * s;
            if (d == 0) s2_0 = s2;
            uf = uf && (s2 == s2_0);
            ld += log2f(s2);
        }
    }

    if (__all((int)uf)) {
        const float w0 = 1.0f / s2_0;
        v4f A[D_ / 4];
        float b = 0.f;
        {
            const v4f* cg = (const v4f*)(centers + (size_t)m * D_);
            #pragma unroll
            for (int j = 0; j < D_ / 4; ++j) {
                v4f c = cg[j];
                v4f a = c * w0;
                A[j] = a;
                b = fmaf(c.x, a.x, b);
                b = fmaf(c.y, a.y, b);
                b = fmaf(c.z, a.z, b);
                b = fmaf(c.w, a.w, b);
            }
        }
        // Register barrier: compiler cannot rematerialize A from the centers
        // loads -> A stays VGPR-resident across the loop (round-4 lesson).
        #pragma unroll
        for (int j = 0; j < D_ / 4; ++j) PIN(A[j]);

        const float c0 = fmaf(-0.5f * L2E, b, -0.5f * (D_ * LOG2_2PI + ld));
        const float qc = -0.5f * L2E * w0;

        const v4f* r2v = (const v4f*)r2s;
        float* o0 = out + (size_t)n0 * M_ + m;
        #pragma unroll 1
        for (int i = 0; i < NT; i += 4) {
            const v4f* xr = (const v4f*)(xs + (size_t)i * D_);  // uniform addr
            v4f acc0 = {0.f,0.f,0.f,0.f}, acc1 = {0.f,0.f,0.f,0.f};
            v4f acc2 = {0.f,0.f,0.f,0.f}, acc3 = {0.f,0.f,0.f,0.f};
            #pragma unroll
            for (int j = 0; j < D_ / 4; ++j) {
                v4f aj = A[j];
                acc0 += xr[j]      * aj;   // 2x v_pk_fma_f32 each
                acc1 += xr[j + 8]  * aj;
                acc2 += xr[j + 16] * aj;
                acc3 += xr[j + 24] * aj;
            }
            v4f rr = r2v[i >> 2];          // r2s[i..i+3] in one ds_read_b128
            float d0 = (acc0.x + acc0.y) + (acc0.z + acc0.w);
            float d1 = (acc1.x + acc1.y) + (acc1.z + acc1.w);
            float d2 = (acc2.x + acc2.y) + (acc2.z + acc2.w);
            float d3 = (acc3.x + acc3.y) + (acc3.z + acc3.w);
            float f0 = fmaf(L2E, d0, fmaf(qc, rr.x, c0));
            float f1 = fmaf(L2E, d1, fmaf(qc, rr.y, c0));
            float f2 = fmaf(L2E, d2, fmaf(qc, rr.z, c0));
            float f3 = fmaf(L2E, d3, fmaf(qc, rr.w, c0));
            __builtin_nontemporal_store(__builtin_amdgcn_exp2f(f0), o0 + (size_t)(i    ) * M_);
            __builtin_nontemporal_store(__builtin_amdgcn_exp2f(f1), o0 + (size_t)(i + 1) * M_);
            __builtin_nontemporal_store(__builtin_amdgcn_exp2f(f2), o0 + (size_t)(i + 2) * M_);
            __builtin_nontemporal_store(__builtin_amdgcn_exp2f(f3), o0 + (size_t)(i + 3) * M_);
        }
    } else {
        // general path: correct for arbitrary sigma, register-frugal
        const float c0 = -0.5f * (D_ * LOG2_2PI + ld);
        const float* cg = centers + (size_t)m * D_;
        const float* sg = sigma   + (size_t)m * D_;
        #pragma unroll 1
        for (int i = 0; i < NT; ++i) {
            const float* xr = xs + (size_t)i * D_;
            float a0 = 0.f, a1 = 0.f;
            #pragma unroll
            for (int d = 0; d < D_; d += 2) {
                float s0 = sg[d], s1 = sg[d + 1];
                float t0 = xr[d]     - cg[d];
                float t1 = xr[d + 1] - cg[d + 1];
                a0 = fmaf(t0 * (1.0f / (s0 * s0)), t0, a0);
                a1 = fmaf(t1 * (1.0f / (s1 * s1)), t1, a1);
            }
            float f = fmaf(-0.5f * L2E, a0 + a1, c0);
            out[(size_t)(n0 + i) * M_ + m] = __builtin_amdgcn_exp2f(f);
        }
    }
}

extern "C" void kernel_launch(void* const* d_in, const int* in_sizes, int n_in,
                              void* d_out, int out_size, void* d_ws, size_t ws_size,
                              hipStream_t stream) {
    const float* x = (const float*)d_in[0];
    const float* c = (const float*)d_in[1];
    const float* s = (const float*)d_in[2];
    float* out = (float*)d_out;
    dim3 grid(M_ / BLK, N_ / NT);
    rbf_kernel<<<grid, BLK, 0, stream>>>(x, c, s, out);
}

// Round 2
// 96.095 us; speedup vs baseline: 1.0003x; 1.0003x over previous
//
#include <hip/hip_runtime.h>

// out[n,m] = exp(-0.5 * sum_d (x[n,d]-c[m,d])^2 / s2[m,d]) / sqrt((2pi)^D * prod s2[m,d])
// Fast path (per-center d-uniform variance; true for bench sigma==1):
//   out = exp2( L2E*(x.a) + qc*r2[n] + c0 ),  a = c/s2, qc = -0.5*L2E/s2,
//   c0 = -0.5*L2E*(c.a) - 0.5*(D*log2(2pi) + sum log2 s2),  r2[n] = sum_d x^2
//
// Round 6 theory: x[n,:] is WAVE-UNIFORM in the inner loop. Both previous
// versions broadcast it to all 64 lanes every row (global uniform loads /
// ds_read_b128 broadcasts) -- ~8k shared-port ops per CU ~= the observed
// ~36us plateau, identical for both media. Fix: x rows come in via wide
// SCALAR loads (uniform address + __restrict readonly -> s_load_dwordx16)
// and feed v_pk_fma as the one legal SGPR operand. Zero per-lane x traffic.
// 8-row batches amortize the single lgkmcnt(0) drain (SMEM is out-of-order).
// NT=32 -> grid 2048 -> up to 8 blocks/CU (VGPRs ~55 now that x is scalar).

#define N_  16384
#define M_  1024
#define D_  32
#define NT  32      // grid = (4, 512) = 2048 blocks -> up to 8 blocks/CU
#define BLK 256

typedef float v4f __attribute__((ext_vector_type(4)));
#define PIN(v) asm volatile("" : "+v"(v))

__global__ __launch_bounds__(BLK, 6) void rbf_kernel(
    const float* __restrict__ x, const float* __restrict__ centers,
    const float* __restrict__ sigma, float* __restrict__ out)
{
    const int tid = threadIdx.x;
    const int m   = blockIdx.x * BLK + tid;
    const int n0  = blockIdx.y * NT;

    __shared__ __align__(16) float r2s[NT];   // 128 B only

    // r2 for the tile's 32 rows: one float4 per thread (8 lanes per row),
    // 8-lane shuffle reduction. Fully coalesced, one pass.
    {
        const v4f* xg = (const v4f*)(x + (size_t)n0 * D_);
        v4f v = xg[tid];
        float s = fmaf(v.x, v.x, fmaf(v.y, v.y, fmaf(v.z, v.z, v.w * v.w)));
        s += __shfl_xor(s, 1);
        s += __shfl_xor(s, 2);
        s += __shfl_xor(s, 4);
        if ((tid & 7) == 0) r2s[tid >> 3] = s;
    }
    __syncthreads();

    const float L2E      = 1.4426950408889634f;   // log2(e)
    const float LOG2_2PI = 2.6514961294723187f;   // log2(2*pi)

    // sigma scan: d-uniform check + log-determinant (exactly 0 for sigma==1)
    float s2_0 = 0.f, ld = 0.f;
    bool uf = true;
    {
        const float* sg = sigma + (size_t)m * D_;
        #pragma unroll
        for (int d = 0; d < D_; ++d) {
            float s  = sg[d];
            float s2 = s * s;
            if (d == 0) s2_0 = s2;
            uf = uf && (s2 == s2_0);
            ld += log2f(s2);
        }
    }

    if (__all((int)uf)) {
        const float w0 = 1.0f / s2_0;
        v4f A[D_ / 4];
        float b = 0.f;
        {
            const v4f* cg = (const v4f*)(centers + (size_t)m * D_);
            #pragma unroll
            for (int j = 0; j < D_ / 4; ++j) {
                v4f c = cg[j];
                v4f a = c * w0;
                A[j] = a;
                b = fmaf(c.x, a.x, b);
                b = fmaf(c.y, a.y, b);
                b = fmaf(c.z, a.z, b);
                b = fmaf(c.w, a.w, b);
            }
        }
        // Register barrier: compiler cannot rematerialize A from the centers
        // loads -> A stays VGPR-resident across the loop (round-4 lesson).
        #pragma unroll
        for (int j = 0; j < D_ / 4; ++j) PIN(A[j]);

        const float c0 = fmaf(-0.5f * L2E, b, -0.5f * (D_ * LOG2_2PI + ld));
        const float qc = -0.5f * L2E * w0;

        const v4f* r2v = (const v4f*)r2s;
        float* o0 = out + (size_t)n0 * M_ + m;

        #pragma unroll 1
        for (int i = 0; i < NT; i += 8) {
            v4f ra = r2v[i / 4];        // r2s[i..i+3]   (one b128 broadcast)
            v4f rb = r2v[i / 4 + 1];    // r2s[i+4..i+7]
            #pragma unroll
            for (int k = 0; k < 8; ++k) {
                // Uniform address off a readonly __restrict pointer:
                // selected as s_load_dwordx4, merged to 2x s_load_dwordx16.
                const v4f* row = (const v4f*)(x + (size_t)(n0 + i + k) * D_);
                v4f x0 = row[0], x1 = row[1], x2 = row[2], x3 = row[3];
                v4f x4 = row[4], x5 = row[5], x6 = row[6], x7 = row[7];
                v4f p = x0 * A[0];
                v4f q = x1 * A[1];
                p += x2 * A[2];  q += x3 * A[3];   // v_pk_fma_f32, SGPR src0
                p += x4 * A[4];  q += x5 * A[5];
                p += x6 * A[6];  q += x7 * A[7];
                v4f t = p + q;
                float dot = (t.x + t.y) + (t.z + t.w);
                float rr  = (k < 4) ? ra[k] : rb[k - 4];   // k is constexpr
                float f   = fmaf(L2E, dot, fmaf(qc, rr, c0));
                __builtin_nontemporal_store(__builtin_amdgcn_exp2f(f),
                                            o0 + (size_t)(i + k) * M_);
            }
        }
    } else {
        // general path: correct for arbitrary sigma, register-frugal
        const float c0 = -0.5f * (D_ * LOG2_2PI + ld);
        const float* cg = centers + (size_t)m * D_;
        const float* sg = sigma   + (size_t)m * D_;
        #pragma unroll 1
        for (int i = 0; i < NT; ++i) {
            const float* xr = x + (size_t)(n0 + i) * D_;
            float a0 = 0.f, a1 = 0.f;
            #pragma unroll
            for (int d = 0; d < D_; d += 2) {
                float s0 = sg[d], s1 = sg[d + 1];
                float t0 = xr[d]     - cg[d];
                float t1 = xr[d + 1] - cg[d + 1];
                a0 = fmaf(t0 * (1.0f / (s0 * s0)), t0, a0);
                a1 = fmaf(t1 * (1.0f / (s1 * s1)), t1, a1);
            }
            float f = fmaf(-0.5f * L2E, a0 + a1, c0);
            out[(size_t)(n0 + i) * M_ + m] = __builtin_amdgcn_exp2f(f);
        }
    }
}

extern "C" void kernel_launch(void* const* d_in, const int* in_sizes, int n_in,
                              void* d_out, int out_size, void* d_ws, size_t ws_size,
                              hipStream_t stream) {
    const float* x = (const float*)d_in[0];
    const float* c = (const float*)d_in[1];
    const float* s = (const float*)d_in[2];
    float* out = (float*)d_out;
    dim3 grid(M_ / BLK, N_ / NT);
    rbf_kernel<<<grid, BLK, 0, stream>>>(x, c, s, out);
}

// Round 3
// 90.196 us; speedup vs baseline: 1.0657x; 1.0654x over previous
//
#include <hip/hip_runtime.h>

// out[n,m] = exp(-0.5 * sum_d (x[n,d]-c[m,d])^2 / s2[m,d]) / sqrt((2pi)^D * prod s2[m,d])
// Fast path (per-center d-uniform variance; true for bench sigma==1):
//   out = exp2( L2E*(x.a) + qc*r2[n] + c0 ),  a = c/s2, qc = -0.5*L2E/s2,
//   c0 = -0.5*L2E*(c.a) - 0.5*(D*log2(2pi) + log2 prod s2),  r2[n] = sum_d x^2
//
// Round 7 theory: rounds 5/6 (x via LDS broadcast / scalar SMEM) were exactly
// neutral -> the shared bottleneck is the PER-M PROLOGUE, re-run by all 512
// y-blocks: 32 lane-stride-128B scalar sigma loads (64 cache lines PER wave
// instruction, ~2k line-transactions/wave) + 8 uncoalesced centers loads +
// 32 serial log2f. ~21M L1 line-transactions ~= the invariant ~25us gap.
// Fix: tiny precompute kernel computes per-m constants ONCE (1024 m's, not
// 512x1024), stores A transposed (m-inner -> coalesced) in the workspace.
// Main-kernel prologue becomes 8 coalesced dwordx4 + 3 dwords (~1us).

#define N_  16384
#define M_  1024
#define D_  32
#define NT  32      // grid = (4, 512) = 2048 blocks -> up to 8 blocks/CU
#define BLK 256

typedef float v4f __attribute__((ext_vector_type(4)));
#define PIN(v) asm volatile("" : "+v"(v))

#define L2E_      1.4426950408889634f   // log2(e)
#define LOG2_2PI_ 2.6514961294723187f   // log2(2*pi)

// ---- workspace layout -------------------------------------------------
// At   : v4f [8][M_]   (A[j] for lane m at At[j*M_+m])   128 KB
// qc   : float [M_]                                        4 KB
// c0f  : float [M_]    (fast-path constant)                4 KB
// g0   : float [M_]    (general-path constant)             4 KB
// flag : int   [M_]    (d-uniform sigma?)                  4 KB
#define WS_NEED (8 * M_ * 16 + 4 * M_ * 4)

__global__ __launch_bounds__(64) void rbf_pre(
    const float* __restrict__ centers, const float* __restrict__ sigma,
    v4f* __restrict__ At, float* __restrict__ qc, float* __restrict__ c0f,
    float* __restrict__ g0, float* __restrict__ flag)
{
    const int m = blockIdx.x * 64 + threadIdx.x;
    const v4f* cg = (const v4f*)(centers + (size_t)m * D_);
    const v4f* sg = (const v4f*)(sigma   + (size_t)m * D_);

    v4f cv[8], s2v[8];
    #pragma unroll
    for (int j = 0; j < 8; ++j) {
        cv[j] = cg[j];
        v4f s = sg[j];
        s2v[j] = s * s;
    }
    const float s2_0 = s2v[0].x;
    bool uf = true;
    float pr = 1.0f;                 // f32 product, same as jnp.prod in ref
    #pragma unroll
    for (int j = 0; j < 8; ++j) {
        #pragma unroll
        for (int e = 0; e < 4; ++e) {
            float v = s2v[j][e];
            uf = uf && (v == s2_0);
            pr *= v;
        }
    }
    const float ld = log2f(pr);

    const float w0 = 1.0f / s2_0;
    float b = 0.f;
    #pragma unroll
    for (int j = 0; j < 8; ++j) {
        v4f a = cv[j] * w0;
        At[(size_t)j * M_ + m] = a;          // m-inner -> coalesced
        b = fmaf(cv[j].x, a.x, b);
        b = fmaf(cv[j].y, a.y, b);
        b = fmaf(cv[j].z, a.z, b);
        b = fmaf(cv[j].w, a.w, b);
    }
    const float g = -0.5f * (D_ * LOG2_2PI_ + ld);
    g0[m]   = g;
    c0f[m]  = fmaf(-0.5f * L2E_, b, g);
    qc[m]   = -0.5f * L2E_ * w0;
    flag[m] = uf ? 1.0f : 0.0f;
}

__global__ __launch_bounds__(BLK, 6) void rbf_main(
    const float* __restrict__ x, const float* __restrict__ centers,
    const float* __restrict__ sigma, float* __restrict__ out,
    const v4f* __restrict__ At, const float* __restrict__ qc,
    const float* __restrict__ c0f, const float* __restrict__ g0,
    const float* __restrict__ flag)
{
    const int tid = threadIdx.x;
    const int m   = blockIdx.x * BLK + tid;
    const int n0  = blockIdx.y * NT;

    __shared__ __align__(16) float r2s[NT];   // 128 B

    // r2 for the tile's 32 rows: one v4f per thread (8 lanes per row),
    // 8-lane shuffle reduction. Fully coalesced, one pass.
    {
        const v4f* xg = (const v4f*)(x + (size_t)n0 * D_);
        v4f v = xg[tid];
        float s = fmaf(v.x, v.x, fmaf(v.y, v.y, fmaf(v.z, v.z, v.w * v.w)));
        s += __shfl_xor(s, 1);
        s += __shfl_xor(s, 2);
        s += __shfl_xor(s, 4);
        if ((tid & 7) == 0) r2s[tid >> 3] = s;
    }
    __syncthreads();

    const float fl = flag[m];          // coalesced
    if (__all(fl != 0.0f)) {
        const float qcm = qc[m];       // coalesced
        const float c0m = c0f[m];      // coalesced
        v4f A[8];
        #pragma unroll
        for (int j = 0; j < 8; ++j) A[j] = At[(size_t)j * M_ + m];  // coalesced x4
        #pragma unroll
        for (int j = 0; j < 8; ++j) PIN(A[j]);   // keep VGPR-resident (round-4 lesson)

        const v4f* r2v = (const v4f*)r2s;
        float* o0 = out + (size_t)n0 * M_ + m;

        #pragma unroll 1
        for (int i = 0; i < NT; i += 8) {
            v4f ra = r2v[i / 4];        // r2s[i..i+3]
            v4f rb = r2v[i / 4 + 1];    // r2s[i+4..i+7]
            #pragma unroll
            for (int k = 0; k < 8; ++k) {
                // Uniform address off readonly __restrict -> scalar loads.
                const v4f* row = (const v4f*)(x + (size_t)(n0 + i + k) * D_);
                v4f x0 = row[0], x1 = row[1], x2 = row[2], x3 = row[3];
                v4f x4 = row[4], x5 = row[5], x6 = row[6], x7 = row[7];
                v4f p = x0 * A[0];
                v4f q = x1 * A[1];
                p += x2 * A[2];  q += x3 * A[3];   // v_pk_fma_f32, SGPR src
                p += x4 * A[4];  q += x5 * A[5];
                p += x6 * A[6];  q += x7 * A[7];
                v4f t = p + q;
                float dot = (t.x + t.y) + (t.z + t.w);
                float rr  = (k < 4) ? ra[k] : rb[k - 4];   // k is constexpr
                float f   = fmaf(L2E_, dot, fmaf(qcm, rr, c0m));
                __builtin_nontemporal_store(__builtin_amdgcn_exp2f(f),
                                            o0 + (size_t)(i + k) * M_);
            }
        }
    } else {
        // general path: correct for arbitrary sigma, register-frugal
        const float c0 = g0[m];
        const float* cg = centers + (size_t)m * D_;
        const float* sg = sigma   + (size_t)m * D_;
        #pragma unroll 1
        for (int i = 0; i < NT; ++i) {
            const float* xr = x + (size_t)(n0 + i) * D_;
            float a0 = 0.f, a1 = 0.f;
            #pragma unroll
            for (int d = 0; d < D_; d += 2) {
                float s0 = sg[d], s1 = sg[d + 1];
                float t0 = xr[d]     - cg[d];
                float t1 = xr[d + 1] - cg[d + 1];
                a0 = fmaf(t0 * (1.0f / (s0 * s0)), t0, a0);
                a1 = fmaf(t1 * (1.0f / (s1 * s1)), t1, a1);
            }
            float f = fmaf(-0.5f * L2E_, a0 + a1, c0);
            out[(size_t)(n0 + i) * M_ + m] = __builtin_amdgcn_exp2f(f);
        }
    }
}

// ---- monolithic fallback (round-6 kernel) if workspace is too small ----
__global__ __launch_bounds__(BLK, 6) void rbf_mono(
    const float* __restrict__ x, const float* __restrict__ centers,
    const float* __restrict__ sigma, float* __restrict__ out)
{
    const int tid = threadIdx.x;
    const int m   = blockIdx.x * BLK + tid;
    const int n0  = blockIdx.y * NT;

    __shared__ __align__(16) float r2s[NT];
    {
        const v4f* xg = (const v4f*)(x + (size_t)n0 * D_);
        v4f v = xg[tid];
        float s = fmaf(v.x, v.x, fmaf(v.y, v.y, fmaf(v.z, v.z, v.w * v.w)));
        s += __shfl_xor(s, 1);
        s += __shfl_xor(s, 2);
        s += __shfl_xor(s, 4);
        if ((tid & 7) == 0) r2s[tid >> 3] = s;
    }
    __syncthreads();

    float s2_0 = 0.f, ld = 0.f;
    bool uf = true;
    {
        const float* sg = sigma + (size_t)m * D_;
        #pragma unroll
        for (int d = 0; d < D_; ++d) {
            float s  = sg[d];
            float s2 = s * s;
            if (d == 0) s2_0 = s2;
            uf = uf && (s2 == s2_0);
            ld += log2f(s2);
        }
    }

    if (__all((int)uf)) {
        const float w0 = 1.0f / s2_0;
        v4f A[8];
        float b = 0.f;
        {
            const v4f* cg = (const v4f*)(centers + (size_t)m * D_);
            #pragma unroll
            for (int j = 0; j < 8; ++j) {
                v4f c = cg[j];
                v4f a = c * w0;
                A[j] = a;
                b = fmaf(c.x, a.x, b); b = fmaf(c.y, a.y, b);
                b = fmaf(c.z, a.z, b); b = fmaf(c.w, a.w, b);
            }
        }
        #pragma unroll
        for (int j = 0; j < 8; ++j) PIN(A[j]);

        const float c0 = fmaf(-0.5f * L2E_, b, -0.5f * (D_ * LOG2_2PI_ + ld));
        const float qc = -0.5f * L2E_ * w0;
        const v4f* r2v = (const v4f*)r2s;
        float* o0 = out + (size_t)n0 * M_ + m;

        #pragma unroll 1
        for (int i = 0; i < NT; i += 8) {
            v4f ra = r2v[i / 4];
            v4f rb = r2v[i / 4 + 1];
            #pragma unroll
            for (int k = 0; k < 8; ++k) {
                const v4f* row = (const v4f*)(x + (size_t)(n0 + i + k) * D_);
                v4f x0 = row[0], x1 = row[1], x2 = row[2], x3 = row[3];
                v4f x4 = row[4], x5 = row[5], x6 = row[6], x7 = row[7];
                v4f p = x0 * A[0];
                v4f q = x1 * A[1];
                p += x2 * A[2];  q += x3 * A[3];
                p += x4 * A[4];  q += x5 * A[5];
                p += x6 * A[6];  q += x7 * A[7];
                v4f t = p + q;
                float dot = (t.x + t.y) + (t.z + t.w);
                float rr  = (k < 4) ? ra[k] : rb[k - 4];
                float f   = fmaf(L2E_, dot, fmaf(qc, rr, c0));
                __builtin_nontemporal_store(__builtin_amdgcn_exp2f(f),
                                            o0 + (size_t)(i + k) * M_);
            }
        }
    } else {
        const float c0 = -0.5f * (D_ * LOG2_2PI_ + ld);
        const float* cg = centers + (size_t)m * D_;
        const float* sg = sigma   + (size_t)m * D_;
        #pragma unroll 1
        for (int i = 0; i < NT; ++i) {
            const float* xr = x + (size_t)(n0 + i) * D_;
            float a0 = 0.f, a1 = 0.f;
            #pragma unroll
            for (int d = 0; d < D_; d += 2) {
                float s0 = sg[d], s1 = sg[d + 1];
                float t0 = xr[d]     - cg[d];
                float t1 = xr[d + 1] - cg[d + 1];
                a0 = fmaf(t0 * (1.0f / (s0 * s0)), t0, a0);
                a1 = fmaf(t1 * (1.0f / (s1 * s1)), t1, a1);
            }
            float f = fmaf(-0.5f * L2E_, a0 + a1, c0);
            out[(size_t)(n0 + i) * M_ + m] = __builtin_amdgcn_exp2f(f);
        }
    }
}

extern "C" void kernel_launch(void* const* d_in, const int* in_sizes, int n_in,
                              void* d_out, int out_size, void* d_ws, size_t ws_size,
                              hipStream_t stream) {
    const float* x = (const float*)d_in[0];
    const float* c = (const float*)d_in[1];
    const float* s = (const float*)d_in[2];
    float* out = (float*)d_out;

    if (ws_size >= (size_t)WS_NEED && d_ws != nullptr) {
        char*  w    = (char*)d_ws;
        v4f*   At   = (v4f*)w;
        float* qc   = (float*)(w + 8 * M_ * 16);
        float* c0f  = qc  + M_;
        float* g0   = c0f + M_;
        float* flag = g0  + M_;
        rbf_pre<<<dim3(M_ / 64), 64, 0, stream>>>(c, s, At, qc, c0f, g0, flag);
        dim3 grid(M_ / BLK, N_ / NT);
        rbf_main<<<grid, BLK, 0, stream>>>(x, c, s, out, At, qc, c0f, g0, flag);
    } else {
        dim3 grid(M_ / BLK, N_ / NT);
        rbf_mono<<<grid, BLK, 0, stream>>>(x, c, s, out);
    }
}